// Round 10
// baseline (75.701 us; speedup 1.0000x reference)
//
#include <hip/hip_runtime.h>
#include <hip/hip_bf16.h>

// SoftModule fused forward, MI355X gfx950 — v10: two-kernel split (ablation).
// K1: S1+S2+T  -> store packed u32 (s_f16 | r0_f16<<16) [B,64] in d_ws.
// K2: We0/A0/combine/Wc0/A1/E1/E2 -> out, reading s/r0 from d_ws.
// Fallback to fused v9 (verified) if ws_size < 18 MB.

using f32x4 = __attribute__((ext_vector_type(4))) float;
using h16x4 = __attribute__((ext_vector_type(4))) _Float16;
using u32x4 = __attribute__((ext_vector_type(4))) unsigned int;
using u32x2 = __attribute__((ext_vector_type(2))) unsigned int;

#define MFMA16(a, b, c) __builtin_amdgcn_mfma_f32_16x16x16f16((a), (b), (c), 0, 0, 0)

__device__ __forceinline__ short h_bits(float f) {
  _Float16 h = (_Float16)f;
  return __builtin_bit_cast(short, h);
}
__device__ __forceinline__ float h2f(unsigned short b) {
  return (float)__builtin_bit_cast(_Float16, b);
}

__device__ __forceinline__ void dma16(const void* g, char* l) {
  __builtin_amdgcn_global_load_lds(
      (const __attribute__((address_space(1))) unsigned int*)g,
      (__attribute__((address_space(3))) unsigned int*)l, 16, 0, 0);
}

// ---------------- weight convert (identical to v9, renamed) -----------------
__global__ void sm_convert_v10(
    const float* __restrict__ Ws1, const float* __restrict__ Ws2, const float* __restrict__ Wt,
    const float* __restrict__ Wa0, const float* __restrict__ Wa1, const float* __restrict__ Wc0,
    const float* __restrict__ We0, const float* __restrict__ We1, const float* __restrict__ We2,
    const float* __restrict__ bs1, const float* __restrict__ bs2, const float* __restrict__ bt,
    const float* __restrict__ ba0, const float* __restrict__ ba1, const float* __restrict__ bc0,
    const float* __restrict__ be0, const float* __restrict__ be1, const float* __restrict__ be2,
    short* __restrict__ wsh, float* __restrict__ biasf) {
  int d = blockIdx.x * 256 + threadIdx.x;
  if (d < 64512) {
    float v;
    if (d < 32768) {             // Bp1 packing (v9 bijection)
      int kk   = d & 3;
      int ntip = (d >> 2) & 1;
      int p    = (d >> 3) & 15;
      int q    = (d >> 7) & 3;
      int pair = (d >> 9) & 1;
      int kb2  = (d >> 10) & 1;
      int c    = d >> 11;
      int k = c * 32 + kb2 * 16 + q * 4 + kk;
      int o = pair * 32 + ntip * 16 + p;
      v = Ws1[k * 64 + o];
    }
    else if (d < 36864) { int r = d - 32768, o = r >> 6, k = r & 63;   v = Ws2[k * 64 + o]; }
    else if (d < 45056) {        // WtP
      int r = d - 36864;
      int kk   = r & 3;
      int ntip = (r >> 2) & 1;
      int p    = (r >> 3) & 15;
      int q    = (r >> 7) & 3;
      int pair = (r >> 9) & 1;
      int kb2  = (r >> 10) & 1;
      int c    = r >> 11;
      int k = c * 32 + kb2 * 16 + q * 4 + kk;
      int o = pair * 32 + ntip * 16 + p;
      v = Wt[k * 64 + o];
    }
    else if (d < 46080) { int r = d - 45056, o = r >> 6, k = r & 63;   v = Wa0[k * 16 + o]; }
    else if (d < 47104) { int r = d - 46080, o = r >> 6, k = r & 63;   v = Wa1[k * 16 + o]; }
    else if (d < 48128) { int r = d - 47104, o = r >> 4, k = r & 15;   v = Wc0[k * 64 + o]; }
    else if (d < 56320) { int r = d - 48128, n = r >> 11, o = (r >> 6) & 31, i = r & 63; v = We0[n * 2048 + i * 32 + o]; }
    else if (d < 60416) { int r = d - 56320, n = r >> 10, o = (r >> 5) & 31, i = r & 31; v = We1[n * 1024 + i * 32 + o]; }
    else                { int r = d - 60416, n = r >> 10, o = (r >> 5) & 31, i = r & 31; v = We2[n * 1024 + i * 32 + o]; }
    wsh[d] = h_bits(v);
  } else if (d < 65184) {
    int r = d - 64512;
    float v;
    if      (r < 64)  v = bs1[r];
    else if (r < 128) v = bs2[r - 64];
    else if (r < 192) v = bt[r - 128];
    else if (r < 208) v = ba0[r - 192];
    else if (r < 224) v = ba1[r - 208];
    else if (r < 288) v = bc0[r - 224];
    else if (r < 416) v = be0[r - 288];
    else if (r < 544) v = be1[r - 416];
    else              v = be2[r - 544];
    biasf[r] = v;
  }
}

// ---------------- K1: S1 + S2 + T -> packed (s, r0) -------------------------
__global__ __launch_bounds__(256) void sm_k1_v10(
    const float* __restrict__ obs, const float* __restrict__ task,
    const short* __restrict__ wsh, const float* __restrict__ biasf,
    unsigned* __restrict__ sr) {
  const int tid  = threadIdx.x;
  const int wave = tid >> 6;
  const int lane = tid & 63;
  const int q    = lane >> 4;
  const int p    = lane & 15;
  const int lrow = wave * 16;
  const int wgrow  = blockIdx.x * 64;
  const int rowblk = wgrow + lrow;

  __shared__ __align__(16) char lds[33280];  // x 8704 | ring 2x12288
  char* x_lds = lds;
  char* ring  = lds + 8704;

  const short* Bp1  = wsh;
  const short* Ws2T = wsh + 32768;
  const short* WtP  = wsh + 36864;
  const float* bs1 = biasf;        const float* bs2 = biasf + 64;
  const float* bt  = biasf + 128;

  const f32x4 z4 = {0.f, 0.f, 0.f, 0.f};

  auto stx  = [&](int row, int col, float v) { *(short*)(x_lds + row * 136 + col * 2) = h_bits(v); };
  auto ldx4 = [&](int row, int k0) -> h16x4 { return *(const h16x4*)(x_lds + row * 136 + k0 * 2); };
  auto ldb  = [&](const short* W, int off) -> h16x4 { return *(const h16x4*)(W + off); };
  auto cvtA = [&](const u32x4& u) -> h16x4 {
    float4 v = __builtin_bit_cast(float4, u);
    h16x4 a;
    a[0] = (_Float16)v.x; a[1] = (_Float16)v.y;
    a[2] = (_Float16)v.z; a[3] = (_Float16)v.w;
    return a;
  };
  auto lo2 = [&](const u32x4& u) -> h16x4 { return __builtin_bit_cast(h16x4, (u32x2){u[0], u[1]}); };
  auto hi2 = [&](const u32x4& u) -> h16x4 { return __builtin_bit_cast(h16x4, (u32x2){u[2], u[3]}); };

  auto stageA = [&](const float* base, int rowlen, int k0, int buf) {
#pragma unroll
    for (int j = 0; j < 2; ++j) {
      int f = j * 256 + wave * 64 + lane;
      int row = f >> 3;
      int cl = (f & 7) ^ (row & 7);
      dma16(base + (size_t)(wgrow + row) * rowlen + k0 + cl * 4,
            ring + buf * 12288 + j * 4096 + wave * 1024);
    }
  };
  auto stageB = [&](const short* bsrc, int c, int buf) {
    dma16((const char*)bsrc + c * 4096 + (wave * 64 + lane) * 16,
          ring + buf * 12288 + 8192 + wave * 1024);
  };
  auto lda_ = [&](int buf, int kb2) -> u32x4 {
    return *(const u32x4*)(ring + buf * 12288 + (lrow + p) * 128 +
                           (((kb2 * 4 + q) ^ (p & 7)) * 16));
  };
  auto ldbs = [&](int buf, int kb2, int pair) -> u32x4 {
    return *(const u32x4*)(ring + buf * 12288 + 8192 + kb2 * 2048 + pair * 1024 + lane * 16);
  };

  // ---- S1 staged loop (verified v9 structure) ----
  f32x4 accX[4] = {z4, z4, z4, z4};
  {
    stageA(obs, 512, 0, 0); stageB(Bp1, 0, 0);
    for (int c = 0; c < 16; ++c) {
      asm volatile("s_waitcnt vmcnt(0)" ::: "memory");
      __builtin_amdgcn_s_barrier();
      __builtin_amdgcn_sched_barrier(0);
      if (c + 1 < 16) {
        stageA(obs, 512, (c + 1) * 32, (c + 1) & 1);
        stageB(Bp1, c + 1, (c + 1) & 1);
      }
      __builtin_amdgcn_sched_barrier(0);
      const int buf = c & 1;
#pragma unroll
      for (int kb2 = 0; kb2 < 2; ++kb2) {
        h16x4 a = cvtA(lda_(buf, kb2));
        u32x4 B0 = ldbs(buf, kb2, 0);
        u32x4 B1 = ldbs(buf, kb2, 1);
        accX[0] = MFMA16(a, lo2(B0), accX[0]);
        accX[1] = MFMA16(a, hi2(B0), accX[1]);
        accX[2] = MFMA16(a, lo2(B1), accX[2]);
        accX[3] = MFMA16(a, hi2(B1), accX[3]);
      }
    }
  }

  stageA(task, 128, 0, 0); stageB(WtP, 0, 0);   // T chunk 0 in flight over S2

#pragma unroll
  for (int nt = 0; nt < 4; ++nt) {
    float bias = bs1[nt * 16 + p];
#pragma unroll
    for (int r = 0; r < 4; ++r)
      stx(lrow + 4 * q + r, nt * 16 + p, fmaxf(accX[nt][r] + bias, 0.f));
  }

  // ---- S2 ----
  f32x4 accS[4] = {z4, z4, z4, z4};
#pragma unroll
  for (int kb = 0; kb < 4; ++kb) {
    h16x4 a = ldx4(lrow + p, kb * 16 + q * 4);
#pragma unroll
    for (int nt = 0; nt < 4; ++nt)
      accS[nt] = MFMA16(a, ldb(Ws2T, (nt * 16 + p) * 64 + kb * 16 + q * 4), accS[nt]);
  }
  float sf[4][4];
#pragma unroll
  for (int nt = 0; nt < 4; ++nt) {
    float bias = bs2[nt * 16 + p];
#pragma unroll
    for (int r = 0; r < 4; ++r) sf[nt][r] = fmaxf(accS[nt][r] + bias, 0.f);
  }

  // ---- T staged loop ----
  f32x4 accT[4] = {z4, z4, z4, z4};
  {
    for (int c = 0; c < 4; ++c) {
      asm volatile("s_waitcnt vmcnt(0)" ::: "memory");
      __builtin_amdgcn_s_barrier();
      __builtin_amdgcn_sched_barrier(0);
      if (c + 1 < 4) {
        stageA(task, 128, (c + 1) * 32, (c + 1) & 1);
        stageB(WtP, c + 1, (c + 1) & 1);
      }
      __builtin_amdgcn_sched_barrier(0);
      const int buf = c & 1;
#pragma unroll
      for (int kb2 = 0; kb2 < 2; ++kb2) {
        h16x4 a = cvtA(lda_(buf, kb2));
        u32x4 B0 = ldbs(buf, kb2, 0);
        u32x4 B1 = ldbs(buf, kb2, 1);
        accT[0] = MFMA16(a, lo2(B0), accT[0]);
        accT[1] = MFMA16(a, hi2(B0), accT[1]);
        accT[2] = MFMA16(a, lo2(B1), accT[2]);
        accT[3] = MFMA16(a, hi2(B1), accT[3]);
      }
    }
  }

  // ---- r0 = s * relu(t); store packed ----
#pragma unroll
  for (int nt = 0; nt < 4; ++nt) {
    float bias = bt[nt * 16 + p];
#pragma unroll
    for (int r = 0; r < 4; ++r) {
      float tv = fmaxf(accT[nt][r] + bias, 0.f);
      float r0 = sf[nt][r] * tv;
      unsigned pk = (unsigned)(unsigned short)h_bits(sf[nt][r]) |
                    ((unsigned)(unsigned short)h_bits(r0) << 16);
      sr[(size_t)(rowblk + 4 * q + r) * 64 + nt * 16 + p] = pk;
    }
  }
}

// ---------------- K2: We0/A0/combine/Wc0/A1/E1/E2 -> out --------------------
__global__ __launch_bounds__(256) void sm_k2_v10(
    const unsigned* __restrict__ sr, const short* __restrict__ wsh,
    const float* __restrict__ biasf, float* __restrict__ out) {
  const int tid  = threadIdx.x;
  const int wave = tid >> 6;
  const int lane = tid & 63;
  const int q    = lane >> 4;
  const int p    = lane & 15;
  const int lrow = wave * 16;
  const int rowblk = blockIdx.x * 64 + lrow;

  // LDS 20480: pre-barrier x[64,136] @0 | a[64,48] @8704; post: p[4][64,80] @0
  __shared__ __align__(16) char lds[20480];
  char* x_lds = lds;
  char* a_lds = lds + 8704;
  char* p_lds = lds;

  const short* Wa0T = wsh + 45056;
  const short* Wa1T = wsh + 46080;
  const short* Wc0T = wsh + 47104;
  const short* We0T = wsh + 48128;
  const short* We1T = wsh + 56320;
  const short* We2T = wsh + 60416;
  const float* ba0 = biasf + 192;  const float* ba1 = biasf + 208;
  const float* bc0 = biasf + 224;  const float* be0 = biasf + 288;
  const float* be1 = biasf + 416;  const float* be2 = biasf + 544;

  const f32x4 z4 = {0.f, 0.f, 0.f, 0.f};

  auto stx  = [&](int row, int col, float v) { *(short*)(x_lds + row * 136 + col * 2) = h_bits(v); };
  auto ldx4 = [&](int row, int k0) -> h16x4 { return *(const h16x4*)(x_lds + row * 136 + k0 * 2); };
  auto ldb  = [&](const short* W, int off) -> h16x4 { return *(const h16x4*)(W + off); };
  auto lo16 = [&](unsigned a, unsigned b) -> unsigned { return (a & 0xffffu) | (b << 16); };
  auto hi16 = [&](unsigned a, unsigned b) -> unsigned { return (a >> 16) | (b & 0xffff0000u); };

  // ---- load s / r0 A-fragments (row p) and r0 C/D values ----
  h16x4 sA[4], rA[4];
#pragma unroll
  for (int kb = 0; kb < 4; ++kb) {
    u32x4 v = *(const u32x4*)(sr + (size_t)(rowblk + p) * 64 + kb * 16 + q * 4);
    sA[kb] = __builtin_bit_cast(h16x4, (u32x2){lo16(v[0], v[1]), lo16(v[2], v[3])});
    rA[kb] = __builtin_bit_cast(h16x4, (u32x2){hi16(v[0], v[1]), hi16(v[2], v[3])});
  }
  float r0f[4][4];
#pragma unroll
  for (int nt = 0; nt < 4; ++nt)
#pragma unroll
    for (int r = 0; r < 4; ++r) {
      unsigned v = sr[(size_t)(rowblk + 4 * q + r) * 64 + nt * 16 + p];
      r0f[nt][r] = h2f((unsigned short)(v >> 16));
    }

  // ---- We0: m[j] = relu(s @ We0[j] + be0[j]) ----
  float mfr[4][2][4];
#pragma unroll
  for (int n = 0; n < 4; ++n) {
    f32x4 acc[2] = {z4, z4};
#pragma unroll
    for (int kb = 0; kb < 4; ++kb)
#pragma unroll
      for (int nt = 0; nt < 2; ++nt)
        acc[nt] = MFMA16(sA[kb], ldb(We0T, (n * 32 + nt * 16 + p) * 64 + kb * 16 + q * 4), acc[nt]);
#pragma unroll
    for (int nt = 0; nt < 2; ++nt) {
      float bias = be0[n * 32 + nt * 16 + p];
#pragma unroll
      for (int r = 0; r < 4; ++r) mfr[n][nt][r] = fmaxf(acc[nt][r] + bias, 0.f);
    }
  }

  // ---- A0: softmax over groups of 4 of (r0 @ Wa0 + ba0) ----
  f32x4 accA = z4;
#pragma unroll
  for (int kb = 0; kb < 4; ++kb)
    accA = MFMA16(rA[kb], ldb(Wa0T, p * 64 + kb * 16 + q * 4), accA);
  float a0v[4];
  {
    float bias = ba0[p];
#pragma unroll
    for (int r = 0; r < 4; ++r) {
      float v = accA[r] + bias;
      float mx = fmaxf(v, __shfl_xor(v, 1));
      mx = fmaxf(mx, __shfl_xor(mx, 2));
      float e = __expf(v - mx);
      float ssum = e + __shfl_xor(e, 1);
      ssum += __shfl_xor(ssum, 2);
      a0v[r] = e / ssum;
    }
  }
#pragma unroll
  for (int r = 0; r < 4; ++r)
    *(short*)(a_lds + (lrow + 4 * q + r) * 48 + p * 2) = h_bits(a0v[r]);

  // ---- combine ----
  float pv[4][2][4];
#pragma unroll
  for (int i = 0; i < 4; ++i)
#pragma unroll
    for (int nt = 0; nt < 2; ++nt)
#pragma unroll
      for (int r = 0; r < 4; ++r) pv[i][nt][r] = 0.f;
  const int sbase = lane & 48;
#pragma unroll
  for (int r = 0; r < 4; ++r) {
#pragma unroll
    for (int c = 0; c < 16; ++c) {
      float av = __shfl(a0v[r], sbase | c);
      pv[c >> 2][0][r] += av * mfr[c & 3][0][r];
      pv[c >> 2][1][r] += av * mfr[c & 3][1][r];
    }
  }

  // ---- Wc0: r = relu((a0 @ Wc0 + bc0) * r0) ----
  f32x4 accC[4] = {z4, z4, z4, z4};
  {
    h16x4 a = *(const h16x4*)(a_lds + (lrow + p) * 48 + q * 8);
#pragma unroll
    for (int nt = 0; nt < 4; ++nt)
      accC[nt] = MFMA16(a, ldb(Wc0T, (nt * 16 + p) * 16 + q * 4), accC[nt]);
  }
  float rf[4][4];
#pragma unroll
  for (int nt = 0; nt < 4; ++nt) {
    float bias = bc0[nt * 16 + p];
#pragma unroll
    for (int r = 0; r < 4; ++r)
      rf[nt][r] = fmaxf((accC[nt][r] + bias) * r0f[nt][r], 0.f);
  }
#pragma unroll
  for (int nt = 0; nt < 4; ++nt)
#pragma unroll
    for (int r = 0; r < 4; ++r) stx(lrow + 4 * q + r, nt * 16 + p, rf[nt][r]);

  // ---- A1 ----
  f32x4 accA1 = z4;
#pragma unroll
  for (int kb = 0; kb < 4; ++kb)
    accA1 = MFMA16(ldx4(lrow + p, kb * 16 + q * 4), ldb(Wa1T, p * 64 + kb * 16 + q * 4), accA1);
  float a1v[4];
  {
    float bias = ba1[p];
#pragma unroll
    for (int r = 0; r < 4; ++r) {
      float v = accA1[r] + bias;
      float mx = fmaxf(v, __shfl_xor(v, 1));
      mx = fmaxf(mx, __shfl_xor(mx, 2));
      float e = __expf(v - mx);
      float ssum = e + __shfl_xor(e, 1);
      ssum += __shfl_xor(ssum, 2);
      a1v[r] = e / ssum;
    }
  }

  __syncthreads();   // x/a dead; p_lds overlays

  // ---- E1 ----
#pragma unroll
  for (int i = 0; i < 4; ++i)
#pragma unroll
    for (int nt = 0; nt < 2; ++nt)
#pragma unroll
      for (int r = 0; r < 4; ++r)
        *(short*)(p_lds + (i * 64 + lrow + 4 * q + r) * 80 + (nt * 16 + p) * 2) = h_bits(pv[i][nt][r]);

  float m1f[4][2][4];
#pragma unroll
  for (int n = 0; n < 4; ++n) {
    f32x4 acc[2] = {z4, z4};
#pragma unroll
    for (int kb = 0; kb < 2; ++kb) {
      h16x4 a = *(const h16x4*)(p_lds + (n * 64 + lrow + p) * 80 + kb * 32 + q * 8);
#pragma unroll
      for (int nt = 0; nt < 2; ++nt)
        acc[nt] = MFMA16(a, ldb(We1T, (n * 32 + nt * 16 + p) * 32 + kb * 16 + q * 4), acc[nt]);
    }
#pragma unroll
    for (int nt = 0; nt < 2; ++nt) {
      float bias = be1[n * 32 + nt * 16 + p];
#pragma unroll
      for (int r = 0; r < 4; ++r) m1f[n][nt][r] = fmaxf(acc[nt][r] + bias, 0.f);
    }
  }

  // ---- combine 2 ----
#pragma unroll
  for (int i = 0; i < 4; ++i)
#pragma unroll
    for (int nt = 0; nt < 2; ++nt)
#pragma unroll
      for (int r = 0; r < 4; ++r) pv[i][nt][r] = 0.f;
#pragma unroll
  for (int r = 0; r < 4; ++r) {
#pragma unroll
    for (int c = 0; c < 16; ++c) {
      float av = __shfl(a1v[r], sbase | c);
      pv[c >> 2][0][r] += av * m1f[c & 3][0][r];
      pv[c >> 2][1][r] += av * m1f[c & 3][1][r];
    }
  }

  // ---- E2 + sum + store ----
#pragma unroll
  for (int i = 0; i < 4; ++i)
#pragma unroll
    for (int nt = 0; nt < 2; ++nt)
#pragma unroll
      for (int r = 0; r < 4; ++r)
        *(short*)(p_lds + (i * 64 + lrow + 4 * q + r) * 80 + (nt * 16 + p) * 2) = h_bits(pv[i][nt][r]);

  float of[2][4] = {{0.f, 0.f, 0.f, 0.f}, {0.f, 0.f, 0.f, 0.f}};
#pragma unroll
  for (int n = 0; n < 4; ++n) {
    f32x4 acc[2] = {z4, z4};
#pragma unroll
    for (int kb = 0; kb < 2; ++kb) {
      h16x4 a = *(const h16x4*)(p_lds + (n * 64 + lrow + p) * 80 + kb * 32 + q * 8);
#pragma unroll
      for (int nt = 0; nt < 2; ++nt)
        acc[nt] = MFMA16(a, ldb(We2T, (n * 32 + nt * 16 + p) * 32 + kb * 16 + q * 4), acc[nt]);
    }
#pragma unroll
    for (int nt = 0; nt < 2; ++nt) {
      float bias = be2[n * 32 + nt * 16 + p];
#pragma unroll
      for (int r = 0; r < 4; ++r) of[nt][r] += fmaxf(acc[nt][r] + bias, 0.f);
    }
  }
#pragma unroll
  for (int nt = 0; nt < 2; ++nt)
#pragma unroll
    for (int r = 0; r < 4; ++r) {
      int grow = rowblk + 4 * q + r;
      out[(size_t)grow * 32 + nt * 16 + p] = of[nt][r];
    }
}

// ---------------- fallback: verified fused v9 -------------------------------
__global__ __launch_bounds__(256) void sm_fused_v10fb(
    const float* __restrict__ obs, const float* __restrict__ task,
    const short* __restrict__ wsh, const float* __restrict__ biasf,
    float* __restrict__ out) {
  const int tid  = threadIdx.x;
  const int wave = tid >> 6;
  const int lane = tid & 63;
  const int q    = lane >> 4;
  const int p    = lane & 15;
  const int lrow = wave * 16;
  const int wgrow  = blockIdx.x * 64;
  const int rowblk = wgrow + lrow;

  __shared__ __align__(16) char lds[36352];
  char* x_lds = lds;
  char* a_lds = lds + 8704;
  char* ring  = lds + 11776;
  char* p_lds = lds;

  const short* Bp1  = wsh;
  const short* Ws2T = wsh + 32768;
  const short* WtP  = wsh + 36864;
  const short* Wa0T = wsh + 45056;
  const short* Wa1T = wsh + 46080;
  const short* Wc0T = wsh + 47104;
  const short* We0T = wsh + 48128;
  const short* We1T = wsh + 56320;
  const short* We2T = wsh + 60416;
  const float* bs1 = biasf;        const float* bs2 = biasf + 64;
  const float* bt  = biasf + 128;  const float* ba0 = biasf + 192;
  const float* ba1 = biasf + 208;  const float* bc0 = biasf + 224;
  const float* be0 = biasf + 288;  const float* be1 = biasf + 416;
  const float* be2 = biasf + 544;

  const f32x4 z4 = {0.f, 0.f, 0.f, 0.f};

  auto stx  = [&](int row, int col, float v) { *(short*)(x_lds + row * 136 + col * 2) = h_bits(v); };
  auto ldx4 = [&](int row, int k0) -> h16x4 { return *(const h16x4*)(x_lds + row * 136 + k0 * 2); };
  auto ldb  = [&](const short* W, int off) -> h16x4 { return *(const h16x4*)(W + off); };
  auto cvtA = [&](const u32x4& u) -> h16x4 {
    float4 v = __builtin_bit_cast(float4, u);
    h16x4 a;
    a[0] = (_Float16)v.x; a[1] = (_Float16)v.y;
    a[2] = (_Float16)v.z; a[3] = (_Float16)v.w;
    return a;
  };
  auto lo2 = [&](const u32x4& u) -> h16x4 { return __builtin_bit_cast(h16x4, (u32x2){u[0], u[1]}); };
  auto hi2 = [&](const u32x4& u) -> h16x4 { return __builtin_bit_cast(h16x4, (u32x2){u[2], u[3]}); };

  auto stageA = [&](const float* base, int rowlen, int k0, int buf) {
#pragma unroll
    for (int j = 0; j < 2; ++j) {
      int f = j * 256 + wave * 64 + lane;
      int row = f >> 3;
      int cl = (f & 7) ^ (row & 7);
      dma16(base + (size_t)(wgrow + row) * rowlen + k0 + cl * 4,
            ring + buf * 12288 + j * 4096 + wave * 1024);
    }
  };
  auto stageB = [&](const short* bsrc, int c, int buf) {
    dma16((const char*)bsrc + c * 4096 + (wave * 64 + lane) * 16,
          ring + buf * 12288 + 8192 + wave * 1024);
  };
  auto lda_ = [&](int buf, int kb2) -> u32x4 {
    return *(const u32x4*)(ring + buf * 12288 + (lrow + p) * 128 +
                           (((kb2 * 4 + q) ^ (p & 7)) * 16));
  };
  auto ldbs = [&](int buf, int kb2, int pair) -> u32x4 {
    return *(const u32x4*)(ring + buf * 12288 + 8192 + kb2 * 2048 + pair * 1024 + lane * 16);
  };

  f32x4 accX[4] = {z4, z4, z4, z4};
  {
    stageA(obs, 512, 0, 0); stageB(Bp1, 0, 0);
    for (int c = 0; c < 16; ++c) {
      asm volatile("s_waitcnt vmcnt(0)" ::: "memory");
      __builtin_amdgcn_s_barrier();
      __builtin_amdgcn_sched_barrier(0);
      if (c + 1 < 16) {
        stageA(obs, 512, (c + 1) * 32, (c + 1) & 1);
        stageB(Bp1, c + 1, (c + 1) & 1);
      }
      __builtin_amdgcn_sched_barrier(0);
      const int buf = c & 1;
#pragma unroll
      for (int kb2 = 0; kb2 < 2; ++kb2) {
        h16x4 a = cvtA(lda_(buf, kb2));
        u32x4 B0 = ldbs(buf, kb2, 0);
        u32x4 B1 = ldbs(buf, kb2, 1);
        accX[0] = MFMA16(a, lo2(B0), accX[0]);
        accX[1] = MFMA16(a, hi2(B0), accX[1]);
        accX[2] = MFMA16(a, lo2(B1), accX[2]);
        accX[3] = MFMA16(a, hi2(B1), accX[3]);
      }
    }
  }
  stageA(task, 128, 0, 0); stageB(WtP, 0, 0);
#pragma unroll
  for (int nt = 0; nt < 4; ++nt) {
    float bias = bs1[nt * 16 + p];
#pragma unroll
    for (int r = 0; r < 4; ++r)
      stx(lrow + 4 * q + r, nt * 16 + p, fmaxf(accX[nt][r] + bias, 0.f));
  }
  f32x4 accS[4] = {z4, z4, z4, z4};
#pragma unroll
  for (int kb = 0; kb < 4; ++kb) {
    h16x4 a = ldx4(lrow + p, kb * 16 + q * 4);
#pragma unroll
    for (int nt = 0; nt < 4; ++nt)
      accS[nt] = MFMA16(a, ldb(Ws2T, (nt * 16 + p) * 64 + kb * 16 + q * 4), accS[nt]);
  }
  float sf[4][4];
#pragma unroll
  for (int nt = 0; nt < 4; ++nt) {
    float bias = bs2[nt * 16 + p];
#pragma unroll
    for (int r = 0; r < 4; ++r) sf[nt][r] = fmaxf(accS[nt][r] + bias, 0.f);
  }
#pragma unroll
  for (int nt = 0; nt < 4; ++nt)
#pragma unroll
    for (int r = 0; r < 4; ++r) stx(lrow + 4 * q + r, nt * 16 + p, sf[nt][r]);
  f32x4 accT[4] = {z4, z4, z4, z4};
  {
    for (int c = 0; c < 4; ++c) {
      asm volatile("s_waitcnt vmcnt(0)" ::: "memory");
      __builtin_amdgcn_s_barrier();
      __builtin_amdgcn_sched_barrier(0);
      if (c + 1 < 4) {
        stageA(task, 128, (c + 1) * 32, (c + 1) & 1);
        stageB(WtP, c + 1, (c + 1) & 1);
      }
      __builtin_amdgcn_sched_barrier(0);
      const int buf = c & 1;
#pragma unroll
      for (int kb2 = 0; kb2 < 2; ++kb2) {
        h16x4 a = cvtA(lda_(buf, kb2));
        u32x4 B0 = ldbs(buf, kb2, 0);
        u32x4 B1 = ldbs(buf, kb2, 1);
        accT[0] = MFMA16(a, lo2(B0), accT[0]);
        accT[1] = MFMA16(a, hi2(B0), accT[1]);
        accT[2] = MFMA16(a, lo2(B1), accT[2]);
        accT[3] = MFMA16(a, hi2(B1), accT[3]);
      }
    }
  }
  float r0f[4][4];
#pragma unroll
  for (int nt = 0; nt < 4; ++nt) {
    float bias = bt[nt * 16 + p];
#pragma unroll
    for (int r = 0; r < 4; ++r)
      r0f[nt][r] = sf[nt][r] * fmaxf(accT[nt][r] + bias, 0.f);
  }
  float mfr[4][2][4];
#pragma unroll
  for (int n = 0; n < 4; ++n) {
    f32x4 acc[2] = {z4, z4};
#pragma unroll
    for (int kb = 0; kb < 4; ++kb) {
      h16x4 a = ldx4(lrow + p, kb * 16 + q * 4);
#pragma unroll
      for (int nt = 0; nt < 2; ++nt)
        acc[nt] = MFMA16(a, ldb(We0T, (n * 32 + nt * 16 + p) * 64 + kb * 16 + q * 4), acc[nt]);
    }
#pragma unroll
    for (int nt = 0; nt < 2; ++nt) {
      float bias = be0[n * 32 + nt * 16 + p];
#pragma unroll
      for (int r = 0; r < 4; ++r) mfr[n][nt][r] = fmaxf(acc[nt][r] + bias, 0.f);
    }
  }
#pragma unroll
  for (int nt = 0; nt < 4; ++nt)
#pragma unroll
    for (int r = 0; r < 4; ++r) stx(lrow + 4 * q + r, nt * 16 + p, r0f[nt][r]);
  f32x4 accA = z4;
#pragma unroll
  for (int kb = 0; kb < 4; ++kb)
    accA = MFMA16(ldx4(lrow + p, kb * 16 + q * 4), ldb(Wa0T, p * 64 + kb * 16 + q * 4), accA);
  float a0v[4];
  {
    float bias = ba0[p];
#pragma unroll
    for (int r = 0; r < 4; ++r) {
      float v = accA[r] + bias;
      float mx = fmaxf(v, __shfl_xor(v, 1));
      mx = fmaxf(mx, __shfl_xor(mx, 2));
      float e = __expf(v - mx);
      float ssum = e + __shfl_xor(e, 1);
      ssum += __shfl_xor(ssum, 2);
      a0v[r] = e / ssum;
    }
  }
#pragma unroll
  for (int r = 0; r < 4; ++r)
    *(short*)(a_lds + (lrow + 4 * q + r) * 48 + p * 2) = h_bits(a0v[r]);
  float pv[4][2][4];
#pragma unroll
  for (int i = 0; i < 4; ++i)
#pragma unroll
    for (int nt = 0; nt < 2; ++nt)
#pragma unroll
      for (int r = 0; r < 4; ++r) pv[i][nt][r] = 0.f;
  const int sbase = lane & 48;
#pragma unroll
  for (int r = 0; r < 4; ++r) {
#pragma unroll
    for (int c = 0; c < 16; ++c) {
      float av = __shfl(a0v[r], sbase | c);
      pv[c >> 2][0][r] += av * mfr[c & 3][0][r];
      pv[c >> 2][1][r] += av * mfr[c & 3][1][r];
    }
  }
  f32x4 accC[4] = {z4, z4, z4, z4};
  {
    h16x4 a = *(const h16x4*)(a_lds + (lrow + p) * 48 + q * 8);
#pragma unroll
    for (int nt = 0; nt < 4; ++nt)
      accC[nt] = MFMA16(a, ldb(Wc0T, (nt * 16 + p) * 16 + q * 4), accC[nt]);
  }
  float rf[4][4];
#pragma unroll
  for (int nt = 0; nt < 4; ++nt) {
    float bias = bc0[nt * 16 + p];
#pragma unroll
    for (int r = 0; r < 4; ++r)
      rf[nt][r] = fmaxf((accC[nt][r] + bias) * r0f[nt][r], 0.f);
  }
#pragma unroll
  for (int nt = 0; nt < 4; ++nt)
#pragma unroll
    for (int r = 0; r < 4; ++r) stx(lrow + 4 * q + r, nt * 16 + p, rf[nt][r]);
  f32x4 accA1 = z4;
#pragma unroll
  for (int kb = 0; kb < 4; ++kb)
    accA1 = MFMA16(ldx4(lrow + p, kb * 16 + q * 4), ldb(Wa1T, p * 64 + kb * 16 + q * 4), accA1);
  float a1v[4];
  {
    float bias = ba1[p];
#pragma unroll
    for (int r = 0; r < 4; ++r) {
      float v = accA1[r] + bias;
      float mx = fmaxf(v, __shfl_xor(v, 1));
      mx = fmaxf(mx, __shfl_xor(mx, 2));
      float e = __expf(v - mx);
      float ssum = e + __shfl_xor(e, 1);
      ssum += __shfl_xor(ssum, 2);
      a1v[r] = e / ssum;
    }
  }
  __syncthreads();
#pragma unroll
  for (int i = 0; i < 4; ++i)
#pragma unroll
    for (int nt = 0; nt < 2; ++nt)
#pragma unroll
      for (int r = 0; r < 4; ++r)
        *(short*)(p_lds + (i * 64 + lrow + 4 * q + r) * 80 + (nt * 16 + p) * 2) = h_bits(pv[i][nt][r]);
  float m1f[4][2][4];
#pragma unroll
  for (int n = 0; n < 4; ++n) {
    f32x4 acc[2] = {z4, z4};
#pragma unroll
    for (int kb = 0; kb < 2; ++kb) {
      h16x4 a = *(const h16x4*)(p_lds + (n * 64 + lrow + p) * 80 + kb * 32 + q * 8);
#pragma unroll
      for (int nt = 0; nt < 2; ++nt)
        acc[nt] = MFMA16(a, ldb(We1T, (n * 32 + nt * 16 + p) * 32 + kb * 16 + q * 4), acc[nt]);
    }
#pragma unroll
    for (int nt = 0; nt < 2; ++nt) {
      float bias = be1[n * 32 + nt * 16 + p];
#pragma unroll
      for (int r = 0; r < 4; ++r) m1f[n][nt][r] = fmaxf(acc[nt][r] + bias, 0.f);
    }
  }
#pragma unroll
  for (int i = 0; i < 4; ++i)
#pragma unroll
    for (int nt = 0; nt < 2; ++nt)
#pragma unroll
      for (int r = 0; r < 4; ++r) pv[i][nt][r] = 0.f;
#pragma unroll
  for (int r = 0; r < 4; ++r) {
#pragma unroll
    for (int c = 0; c < 16; ++c) {
      float av = __shfl(a1v[r], sbase | c);
      pv[c >> 2][0][r] += av * m1f[c & 3][0][r];
      pv[c >> 2][1][r] += av * m1f[c & 3][1][r];
    }
  }
#pragma unroll
  for (int i = 0; i < 4; ++i)
#pragma unroll
    for (int nt = 0; nt < 2; ++nt)
#pragma unroll
      for (int r = 0; r < 4; ++r)
        *(short*)(p_lds + (i * 64 + lrow + 4 * q + r) * 80 + (nt * 16 + p) * 2) = h_bits(pv[i][nt][r]);
  float of[2][4] = {{0.f, 0.f, 0.f, 0.f}, {0.f, 0.f, 0.f, 0.f}};
#pragma unroll
  for (int n = 0; n < 4; ++n) {
    f32x4 acc[2] = {z4, z4};
#pragma unroll
    for (int kb = 0; kb < 2; ++kb) {
      h16x4 a = *(const h16x4*)(p_lds + (n * 64 + lrow + p) * 80 + kb * 32 + q * 8);
#pragma unroll
      for (int nt = 0; nt < 2; ++nt)
        acc[nt] = MFMA16(a, ldb(We2T, (n * 32 + nt * 16 + p) * 32 + kb * 16 + q * 4), acc[nt]);
    }
#pragma unroll
    for (int nt = 0; nt < 2; ++nt) {
      float bias = be2[n * 32 + nt * 16 + p];
#pragma unroll
      for (int r = 0; r < 4; ++r) of[nt][r] += fmaxf(acc[nt][r] + bias, 0.f);
    }
  }
#pragma unroll
  for (int nt = 0; nt < 2; ++nt)
#pragma unroll
    for (int r = 0; r < 4; ++r) {
      int grow = rowblk + 4 * q + r;
      out[(size_t)grow * 32 + nt * 16 + p] = of[nt][r];
    }
}

extern "C" void kernel_launch(void* const* d_in, const int* in_sizes, int n_in,
                              void* d_out, int out_size, void* d_ws, size_t ws_size,
                              hipStream_t stream) {
  (void)in_sizes; (void)n_in; (void)out_size;
  const float* obs  = (const float*)d_in[0];
  const float* task = (const float*)d_in[1];
  const float* Ws1 = (const float*)d_in[2];  const float* bs1 = (const float*)d_in[3];
  const float* Ws2 = (const float*)d_in[4];  const float* bs2 = (const float*)d_in[5];
  const float* Wt  = (const float*)d_in[6];  const float* bt  = (const float*)d_in[7];
  const float* Wa0 = (const float*)d_in[8];  const float* ba0 = (const float*)d_in[9];
  const float* Wa1 = (const float*)d_in[10]; const float* ba1 = (const float*)d_in[11];
  const float* Wc0 = (const float*)d_in[12]; const float* bc0 = (const float*)d_in[13];
  // d_in[14]=Wc1, d_in[15]=bc1: dead code in the reference
  const float* We0 = (const float*)d_in[16]; const float* be0 = (const float*)d_in[17];
  const float* We1 = (const float*)d_in[18]; const float* be1 = (const float*)d_in[19];
  const float* We2 = (const float*)d_in[20]; const float* be2 = (const float*)d_in[21];

  short* wsh   = (short*)d_ws;
  float* biasf = (float*)((char*)d_ws + 129040);

  sm_convert_v10<<<dim3(255), dim3(256), 0, stream>>>(
      Ws1, Ws2, Wt, Wa0, Wa1, Wc0, We0, We1, We2,
      bs1, bs2, bt, ba0, ba1, bc0, be0, be1, be2,
      wsh, biasf);

  const size_t need = (size_t)(1 << 20) + (size_t)65536 * 64 * 4;  // 1MB + 16MB
  if (ws_size >= need) {
    unsigned* sr = (unsigned*)((char*)d_ws + (1 << 20));
    sm_k1_v10<<<dim3(1024), dim3(256), 0, stream>>>(obs, task, wsh, biasf, sr);
    sm_k2_v10<<<dim3(1024), dim3(256), 0, stream>>>(sr, wsh, biasf, (float*)d_out);
  } else {
    sm_fused_v10fb<<<dim3(1024), dim3(256), 0, stream>>>(
        obs, task, wsh, biasf, (float*)d_out);
  }
}

// Round 11
// 73.922 us; speedup vs baseline: 1.0241x; 1.0241x over previous
//
#include <hip/hip_runtime.h>
#include <hip/hip_bf16.h>

// SoftModule fused forward, MI355X gfx950 — v11.
// K1 (v10, verified): S1+S2+T -> packed (s,r0) f16 pairs in d_ws.
// K2 REWRITTEN: single-wave WGs (64 thr, 16 rows, 4096 WGs), ZERO barriers,
// LDS 8.1KB; combine via broadcast ds_read_b128 of a-rows instead of 64
// ds_bpermute. Waves fully independent -> latency stalls overlap across waves.
// Fallback: fused v9 (verified) when ws_size too small.

using f32x4 = __attribute__((ext_vector_type(4))) float;
using h16x4 = __attribute__((ext_vector_type(4))) _Float16;
using h16x8 = __attribute__((ext_vector_type(8))) _Float16;
using u32x4 = __attribute__((ext_vector_type(4))) unsigned int;
using u32x2 = __attribute__((ext_vector_type(2))) unsigned int;

#define MFMA16(a, b, c) __builtin_amdgcn_mfma_f32_16x16x16f16((a), (b), (c), 0, 0, 0)

__device__ __forceinline__ short h_bits(float f) {
  _Float16 h = (_Float16)f;
  return __builtin_bit_cast(short, h);
}
__device__ __forceinline__ float h2f(unsigned short b) {
  return (float)__builtin_bit_cast(_Float16, b);
}

__device__ __forceinline__ void dma16(const void* g, char* l) {
  __builtin_amdgcn_global_load_lds(
      (const __attribute__((address_space(1))) unsigned int*)g,
      (__attribute__((address_space(3))) unsigned int*)l, 16, 0, 0);
}

// ---------------- weight convert (v9/v10, verified) -------------------------
__global__ void sm_convert_v11(
    const float* __restrict__ Ws1, const float* __restrict__ Ws2, const float* __restrict__ Wt,
    const float* __restrict__ Wa0, const float* __restrict__ Wa1, const float* __restrict__ Wc0,
    const float* __restrict__ We0, const float* __restrict__ We1, const float* __restrict__ We2,
    const float* __restrict__ bs1, const float* __restrict__ bs2, const float* __restrict__ bt,
    const float* __restrict__ ba0, const float* __restrict__ ba1, const float* __restrict__ bc0,
    const float* __restrict__ be0, const float* __restrict__ be1, const float* __restrict__ be2,
    short* __restrict__ wsh, float* __restrict__ biasf) {
  int d = blockIdx.x * 256 + threadIdx.x;
  if (d < 64512) {
    float v;
    if (d < 32768) {
      int kk   = d & 3;
      int ntip = (d >> 2) & 1;
      int p    = (d >> 3) & 15;
      int q    = (d >> 7) & 3;
      int pair = (d >> 9) & 1;
      int kb2  = (d >> 10) & 1;
      int c    = d >> 11;
      int k = c * 32 + kb2 * 16 + q * 4 + kk;
      int o = pair * 32 + ntip * 16 + p;
      v = Ws1[k * 64 + o];
    }
    else if (d < 36864) { int r = d - 32768, o = r >> 6, k = r & 63;   v = Ws2[k * 64 + o]; }
    else if (d < 45056) {
      int r = d - 36864;
      int kk   = r & 3;
      int ntip = (r >> 2) & 1;
      int p    = (r >> 3) & 15;
      int q    = (r >> 7) & 3;
      int pair = (r >> 9) & 1;
      int kb2  = (r >> 10) & 1;
      int c    = r >> 11;
      int k = c * 32 + kb2 * 16 + q * 4 + kk;
      int o = pair * 32 + ntip * 16 + p;
      v = Wt[k * 64 + o];
    }
    else if (d < 46080) { int r = d - 45056, o = r >> 6, k = r & 63;   v = Wa0[k * 16 + o]; }
    else if (d < 47104) { int r = d - 46080, o = r >> 6, k = r & 63;   v = Wa1[k * 16 + o]; }
    else if (d < 48128) { int r = d - 47104, o = r >> 4, k = r & 15;   v = Wc0[k * 64 + o]; }
    else if (d < 56320) { int r = d - 48128, n = r >> 11, o = (r >> 6) & 31, i = r & 63; v = We0[n * 2048 + i * 32 + o]; }
    else if (d < 60416) { int r = d - 56320, n = r >> 10, o = (r >> 5) & 31, i = r & 31; v = We1[n * 1024 + i * 32 + o]; }
    else                { int r = d - 60416, n = r >> 10, o = (r >> 5) & 31, i = r & 31; v = We2[n * 1024 + i * 32 + o]; }
    wsh[d] = h_bits(v);
  } else if (d < 65184) {
    int r = d - 64512;
    float v;
    if      (r < 64)  v = bs1[r];
    else if (r < 128) v = bs2[r - 64];
    else if (r < 192) v = bt[r - 128];
    else if (r < 208) v = ba0[r - 192];
    else if (r < 224) v = ba1[r - 208];
    else if (r < 288) v = bc0[r - 224];
    else if (r < 416) v = be0[r - 288];
    else if (r < 544) v = be1[r - 416];
    else              v = be2[r - 544];
    biasf[r] = v;
  }
}

// ---------------- K1: S1 + S2 + T -> packed (s, r0) (v10, verified) ---------
__global__ __launch_bounds__(256) void sm_k1_v11(
    const float* __restrict__ obs, const float* __restrict__ task,
    const short* __restrict__ wsh, const float* __restrict__ biasf,
    unsigned* __restrict__ sr) {
  const int tid  = threadIdx.x;
  const int wave = tid >> 6;
  const int lane = tid & 63;
  const int q    = lane >> 4;
  const int p    = lane & 15;
  const int lrow = wave * 16;
  const int wgrow  = blockIdx.x * 64;
  const int rowblk = wgrow + lrow;

  __shared__ __align__(16) char lds[33280];  // x 8704 | ring 2x12288
  char* x_lds = lds;
  char* ring  = lds + 8704;

  const short* Bp1  = wsh;
  const short* Ws2T = wsh + 32768;
  const short* WtP  = wsh + 36864;
  const float* bs1 = biasf;        const float* bs2 = biasf + 64;
  const float* bt  = biasf + 128;

  const f32x4 z4 = {0.f, 0.f, 0.f, 0.f};

  auto stx  = [&](int row, int col, float v) { *(short*)(x_lds + row * 136 + col * 2) = h_bits(v); };
  auto ldx4 = [&](int row, int k0) -> h16x4 { return *(const h16x4*)(x_lds + row * 136 + k0 * 2); };
  auto ldb  = [&](const short* W, int off) -> h16x4 { return *(const h16x4*)(W + off); };
  auto cvtA = [&](const u32x4& u) -> h16x4 {
    float4 v = __builtin_bit_cast(float4, u);
    h16x4 a;
    a[0] = (_Float16)v.x; a[1] = (_Float16)v.y;
    a[2] = (_Float16)v.z; a[3] = (_Float16)v.w;
    return a;
  };
  auto lo2 = [&](const u32x4& u) -> h16x4 { return __builtin_bit_cast(h16x4, (u32x2){u[0], u[1]}); };
  auto hi2 = [&](const u32x4& u) -> h16x4 { return __builtin_bit_cast(h16x4, (u32x2){u[2], u[3]}); };

  auto stageA = [&](const float* base, int rowlen, int k0, int buf) {
#pragma unroll
    for (int j = 0; j < 2; ++j) {
      int f = j * 256 + wave * 64 + lane;
      int row = f >> 3;
      int cl = (f & 7) ^ (row & 7);
      dma16(base + (size_t)(wgrow + row) * rowlen + k0 + cl * 4,
            ring + buf * 12288 + j * 4096 + wave * 1024);
    }
  };
  auto stageB = [&](const short* bsrc, int c, int buf) {
    dma16((const char*)bsrc + c * 4096 + (wave * 64 + lane) * 16,
          ring + buf * 12288 + 8192 + wave * 1024);
  };
  auto lda_ = [&](int buf, int kb2) -> u32x4 {
    return *(const u32x4*)(ring + buf * 12288 + (lrow + p) * 128 +
                           (((kb2 * 4 + q) ^ (p & 7)) * 16));
  };
  auto ldbs = [&](int buf, int kb2, int pair) -> u32x4 {
    return *(const u32x4*)(ring + buf * 12288 + 8192 + kb2 * 2048 + pair * 1024 + lane * 16);
  };

  f32x4 accX[4] = {z4, z4, z4, z4};
  {
    stageA(obs, 512, 0, 0); stageB(Bp1, 0, 0);
    for (int c = 0; c < 16; ++c) {
      asm volatile("s_waitcnt vmcnt(0)" ::: "memory");
      __builtin_amdgcn_s_barrier();
      __builtin_amdgcn_sched_barrier(0);
      if (c + 1 < 16) {
        stageA(obs, 512, (c + 1) * 32, (c + 1) & 1);
        stageB(Bp1, c + 1, (c + 1) & 1);
      }
      __builtin_amdgcn_sched_barrier(0);
      const int buf = c & 1;
#pragma unroll
      for (int kb2 = 0; kb2 < 2; ++kb2) {
        h16x4 a = cvtA(lda_(buf, kb2));
        u32x4 B0 = ldbs(buf, kb2, 0);
        u32x4 B1 = ldbs(buf, kb2, 1);
        accX[0] = MFMA16(a, lo2(B0), accX[0]);
        accX[1] = MFMA16(a, hi2(B0), accX[1]);
        accX[2] = MFMA16(a, lo2(B1), accX[2]);
        accX[3] = MFMA16(a, hi2(B1), accX[3]);
      }
    }
  }

  stageA(task, 128, 0, 0); stageB(WtP, 0, 0);

#pragma unroll
  for (int nt = 0; nt < 4; ++nt) {
    float bias = bs1[nt * 16 + p];
#pragma unroll
    for (int r = 0; r < 4; ++r)
      stx(lrow + 4 * q + r, nt * 16 + p, fmaxf(accX[nt][r] + bias, 0.f));
  }

  f32x4 accS[4] = {z4, z4, z4, z4};
#pragma unroll
  for (int kb = 0; kb < 4; ++kb) {
    h16x4 a = ldx4(lrow + p, kb * 16 + q * 4);
#pragma unroll
    for (int nt = 0; nt < 4; ++nt)
      accS[nt] = MFMA16(a, ldb(Ws2T, (nt * 16 + p) * 64 + kb * 16 + q * 4), accS[nt]);
  }
  float sf[4][4];
#pragma unroll
  for (int nt = 0; nt < 4; ++nt) {
    float bias = bs2[nt * 16 + p];
#pragma unroll
    for (int r = 0; r < 4; ++r) sf[nt][r] = fmaxf(accS[nt][r] + bias, 0.f);
  }

  f32x4 accT[4] = {z4, z4, z4, z4};
  {
    for (int c = 0; c < 4; ++c) {
      asm volatile("s_waitcnt vmcnt(0)" ::: "memory");
      __builtin_amdgcn_s_barrier();
      __builtin_amdgcn_sched_barrier(0);
      if (c + 1 < 4) {
        stageA(task, 128, (c + 1) * 32, (c + 1) & 1);
        stageB(WtP, c + 1, (c + 1) & 1);
      }
      __builtin_amdgcn_sched_barrier(0);
      const int buf = c & 1;
#pragma unroll
      for (int kb2 = 0; kb2 < 2; ++kb2) {
        h16x4 a = cvtA(lda_(buf, kb2));
        u32x4 B0 = ldbs(buf, kb2, 0);
        u32x4 B1 = ldbs(buf, kb2, 1);
        accT[0] = MFMA16(a, lo2(B0), accT[0]);
        accT[1] = MFMA16(a, hi2(B0), accT[1]);
        accT[2] = MFMA16(a, lo2(B1), accT[2]);
        accT[3] = MFMA16(a, hi2(B1), accT[3]);
      }
    }
  }

#pragma unroll
  for (int nt = 0; nt < 4; ++nt) {
    float bias = bt[nt * 16 + p];
#pragma unroll
    for (int r = 0; r < 4; ++r) {
      float tv = fmaxf(accT[nt][r] + bias, 0.f);
      float r0 = sf[nt][r] * tv;
      unsigned pk = (unsigned)(unsigned short)h_bits(sf[nt][r]) |
                    ((unsigned)(unsigned short)h_bits(r0) << 16);
      sr[(size_t)(rowblk + 4 * q + r) * 64 + nt * 16 + p] = pk;
    }
  }
}

// ---------------- K2 v11: single-wave WG, no barriers -----------------------
__global__ __launch_bounds__(64, 4) void sm_k2_v11(
    const unsigned* __restrict__ sr, const short* __restrict__ wsh,
    const float* __restrict__ biasf, float* __restrict__ out) {
  const int lane = threadIdx.x & 63;
  const int q    = lane >> 4;
  const int p    = lane & 15;
  const int rowblk = blockIdx.x * 16;

  // 1 wave: x[16][136] @0 (2176) | a[16][48] @2176 (768) | pm[4][16][80] @2944
  __shared__ __align__(16) char lds[8192];
  char* x_lds = lds;
  char* a_lds = lds + 2176;
  char* pm_lds = lds + 2944;

  const short* Wa0T = wsh + 45056;
  const short* Wa1T = wsh + 46080;
  const short* Wc0T = wsh + 47104;
  const short* We0T = wsh + 48128;
  const short* We1T = wsh + 56320;
  const short* We2T = wsh + 60416;
  const float* ba0 = biasf + 192;  const float* ba1 = biasf + 208;
  const float* bc0 = biasf + 224;  const float* be0 = biasf + 288;
  const float* be1 = biasf + 416;  const float* be2 = biasf + 544;

  const f32x4 z4 = {0.f, 0.f, 0.f, 0.f};

  auto ldb  = [&](const short* W, int off) -> h16x4 { return *(const h16x4*)(W + off); };
  auto lo16 = [&](unsigned a, unsigned b) -> unsigned { return (a & 0xffffu) | (b << 16); };
  auto hi16 = [&](unsigned a, unsigned b) -> unsigned { return (a >> 16) | (b & 0xffff0000u); };

  // s / r0 A-fragments (row p) + r0 C/D values
  h16x4 sA[4], rA[4];
#pragma unroll
  for (int kb = 0; kb < 4; ++kb) {
    u32x4 v = *(const u32x4*)(sr + (size_t)(rowblk + p) * 64 + kb * 16 + q * 4);
    sA[kb] = __builtin_bit_cast(h16x4, (u32x2){lo16(v[0], v[1]), lo16(v[2], v[3])});
    rA[kb] = __builtin_bit_cast(h16x4, (u32x2){hi16(v[0], v[1]), hi16(v[2], v[3])});
  }
  float r0f[4][4];
#pragma unroll
  for (int nt = 0; nt < 4; ++nt)
#pragma unroll
    for (int r = 0; r < 4; ++r) {
      unsigned v = sr[(size_t)(rowblk + 4 * q + r) * 64 + nt * 16 + p];
      r0f[nt][r] = h2f((unsigned short)(v >> 16));
    }

  // We0
  float mfr[4][2][4];
#pragma unroll
  for (int n = 0; n < 4; ++n) {
    f32x4 acc[2] = {z4, z4};
#pragma unroll
    for (int kb = 0; kb < 4; ++kb)
#pragma unroll
      for (int nt = 0; nt < 2; ++nt)
        acc[nt] = MFMA16(sA[kb], ldb(We0T, (n * 32 + nt * 16 + p) * 64 + kb * 16 + q * 4), acc[nt]);
#pragma unroll
    for (int nt = 0; nt < 2; ++nt) {
      float bias = be0[n * 32 + nt * 16 + p];
#pragma unroll
      for (int r = 0; r < 4; ++r) mfr[n][nt][r] = fmaxf(acc[nt][r] + bias, 0.f);
    }
  }

  // A0 softmax
  f32x4 accA = z4;
#pragma unroll
  for (int kb = 0; kb < 4; ++kb)
    accA = MFMA16(rA[kb], ldb(Wa0T, p * 64 + kb * 16 + q * 4), accA);
  float a0v[4];
  {
    float bias = ba0[p];
#pragma unroll
    for (int r = 0; r < 4; ++r) {
      float v = accA[r] + bias;
      float mx = fmaxf(v, __shfl_xor(v, 1));
      mx = fmaxf(mx, __shfl_xor(mx, 2));
      float e = __expf(v - mx);
      float ssum = e + __shfl_xor(e, 1);
      ssum += __shfl_xor(ssum, 2);
      a0v[r] = e / ssum;
    }
  }
#pragma unroll
  for (int r = 0; r < 4; ++r)
    *(short*)(a_lds + (4 * q + r) * 48 + p * 2) = h_bits(a0v[r]);

  // combine 1: per r, broadcast-read full a0 row (16 f16 = 2x b128)
  float pv[4][2][4];
#pragma unroll
  for (int r = 0; r < 4; ++r) {
    h16x8 a0lo = *(const h16x8*)(a_lds + (4 * q + r) * 48);
    h16x8 a0hi = *(const h16x8*)(a_lds + (4 * q + r) * 48 + 16);
    float av[16];
#pragma unroll
    for (int e = 0; e < 8; ++e) { av[e] = (float)a0lo[e]; av[8 + e] = (float)a0hi[e]; }
#pragma unroll
    for (int i = 0; i < 4; ++i) {
      float s0 = 0.f, s1 = 0.f;
#pragma unroll
      for (int j = 0; j < 4; ++j) {
        s0 += av[4 * i + j] * mfr[j][0][r];
        s1 += av[4 * i + j] * mfr[j][1][r];
      }
      pv[i][0][r] = s0; pv[i][1][r] = s1;
    }
  }

  // Wc0
  f32x4 accC[4] = {z4, z4, z4, z4};
  {
    h16x4 a = *(const h16x4*)(a_lds + p * 48 + q * 8);
#pragma unroll
    for (int nt = 0; nt < 4; ++nt)
      accC[nt] = MFMA16(a, ldb(Wc0T, (nt * 16 + p) * 16 + q * 4), accC[nt]);
  }
  float rf[4][4];
#pragma unroll
  for (int nt = 0; nt < 4; ++nt) {
    float bias = bc0[nt * 16 + p];
#pragma unroll
    for (int r = 0; r < 4; ++r)
      rf[nt][r] = fmaxf((accC[nt][r] + bias) * r0f[nt][r], 0.f);
  }
#pragma unroll
  for (int nt = 0; nt < 4; ++nt)
#pragma unroll
    for (int r = 0; r < 4; ++r)
      *(short*)(x_lds + (4 * q + r) * 136 + (nt * 16 + p) * 2) = h_bits(rf[nt][r]);

  // A1 softmax
  f32x4 accA1 = z4;
#pragma unroll
  for (int kb = 0; kb < 4; ++kb) {
    h16x4 a = *(const h16x4*)(x_lds + p * 136 + (kb * 16 + q * 4) * 2);
    accA1 = MFMA16(a, ldb(Wa1T, p * 64 + kb * 16 + q * 4), accA1);
  }
  float a1v[4];
  {
    float bias = ba1[p];
#pragma unroll
    for (int r = 0; r < 4; ++r) {
      float v = accA1[r] + bias;
      float mx = fmaxf(v, __shfl_xor(v, 1));
      mx = fmaxf(mx, __shfl_xor(mx, 2));
      float e = __expf(v - mx);
      float ssum = e + __shfl_xor(e, 1);
      ssum += __shfl_xor(ssum, 2);
      a1v[r] = e / ssum;
    }
  }
  // a1 -> a_lds (a0 dead after Wc0/combine1; same-wave DS FIFO orders it)
#pragma unroll
  for (int r = 0; r < 4; ++r)
    *(short*)(a_lds + (4 * q + r) * 48 + p * 2) = h_bits(a1v[r]);

  // E1: pv -> pm_lds; m1 = relu(prev1 @ We1 + be1)
#pragma unroll
  for (int i = 0; i < 4; ++i)
#pragma unroll
    for (int nt = 0; nt < 2; ++nt)
#pragma unroll
      for (int r = 0; r < 4; ++r)
        *(short*)(pm_lds + (i * 16 + 4 * q + r) * 80 + (nt * 16 + p) * 2) = h_bits(pv[i][nt][r]);

  float m1f[4][2][4];
#pragma unroll
  for (int n = 0; n < 4; ++n) {
    f32x4 acc[2] = {z4, z4};
#pragma unroll
    for (int kb = 0; kb < 2; ++kb) {
      h16x4 a = *(const h16x4*)(pm_lds + (n * 16 + p) * 80 + kb * 32 + q * 8);
#pragma unroll
      for (int nt = 0; nt < 2; ++nt)
        acc[nt] = MFMA16(a, ldb(We1T, (n * 32 + nt * 16 + p) * 32 + kb * 16 + q * 4), acc[nt]);
    }
#pragma unroll
    for (int nt = 0; nt < 2; ++nt) {
      float bias = be1[n * 32 + nt * 16 + p];
#pragma unroll
      for (int r = 0; r < 4; ++r) m1f[n][nt][r] = fmaxf(acc[nt][r] + bias, 0.f);
    }
  }

  // combine 2 via a_lds broadcast reads
#pragma unroll
  for (int r = 0; r < 4; ++r) {
    h16x8 a1lo = *(const h16x8*)(a_lds + (4 * q + r) * 48);
    h16x8 a1hi = *(const h16x8*)(a_lds + (4 * q + r) * 48 + 16);
    float av[16];
#pragma unroll
    for (int e = 0; e < 8; ++e) { av[e] = (float)a1lo[e]; av[8 + e] = (float)a1hi[e]; }
#pragma unroll
    for (int i = 0; i < 4; ++i) {
      float s0 = 0.f, s1 = 0.f;
#pragma unroll
      for (int j = 0; j < 4; ++j) {
        s0 += av[4 * i + j] * m1f[j][0][r];
        s1 += av[4 * i + j] * m1f[j][1][r];
      }
      pv[i][0][r] = s0; pv[i][1][r] = s1;
    }
  }

  // E2: pv -> pm_lds (overwrite, same-wave ordered); sum over n; store
#pragma unroll
  for (int i = 0; i < 4; ++i)
#pragma unroll
    for (int nt = 0; nt < 2; ++nt)
#pragma unroll
      for (int r = 0; r < 4; ++r)
        *(short*)(pm_lds + (i * 16 + 4 * q + r) * 80 + (nt * 16 + p) * 2) = h_bits(pv[i][nt][r]);

  float of[2][4] = {{0.f, 0.f, 0.f, 0.f}, {0.f, 0.f, 0.f, 0.f}};
#pragma unroll
  for (int n = 0; n < 4; ++n) {
    f32x4 acc[2] = {z4, z4};
#pragma unroll
    for (int kb = 0; kb < 2; ++kb) {
      h16x4 a = *(const h16x4*)(pm_lds + (n * 16 + p) * 80 + kb * 32 + q * 8);
#pragma unroll
      for (int nt = 0; nt < 2; ++nt)
        acc[nt] = MFMA16(a, ldb(We2T, (n * 32 + nt * 16 + p) * 32 + kb * 16 + q * 4), acc[nt]);
    }
#pragma unroll
    for (int nt = 0; nt < 2; ++nt) {
      float bias = be2[n * 32 + nt * 16 + p];
#pragma unroll
      for (int r = 0; r < 4; ++r) of[nt][r] += fmaxf(acc[nt][r] + bias, 0.f);
    }
  }
#pragma unroll
  for (int nt = 0; nt < 2; ++nt)
#pragma unroll
    for (int r = 0; r < 4; ++r) {
      int grow = rowblk + 4 * q + r;
      out[(size_t)grow * 32 + nt * 16 + p] = of[nt][r];
    }
}

// ---------------- fallback: verified fused v9 -------------------------------
__global__ __launch_bounds__(256) void sm_fused_v11fb(
    const float* __restrict__ obs, const float* __restrict__ task,
    const short* __restrict__ wsh, const float* __restrict__ biasf,
    float* __restrict__ out) {
  const int tid  = threadIdx.x;
  const int wave = tid >> 6;
  const int lane = tid & 63;
  const int q    = lane >> 4;
  const int p    = lane & 15;
  const int lrow = wave * 16;
  const int wgrow  = blockIdx.x * 64;
  const int rowblk = wgrow + lrow;

  __shared__ __align__(16) char lds[36352];
  char* x_lds = lds;
  char* a_lds = lds + 8704;
  char* ring  = lds + 11776;
  char* p_lds = lds;

  const short* Bp1  = wsh;
  const short* Ws2T = wsh + 32768;
  const short* WtP  = wsh + 36864;
  const short* Wa0T = wsh + 45056;
  const short* Wa1T = wsh + 46080;
  const short* Wc0T = wsh + 47104;
  const short* We0T = wsh + 48128;
  const short* We1T = wsh + 56320;
  const short* We2T = wsh + 60416;
  const float* bs1 = biasf;        const float* bs2 = biasf + 64;
  const float* bt  = biasf + 128;  const float* ba0 = biasf + 192;
  const float* ba1 = biasf + 208;  const float* bc0 = biasf + 224;
  const float* be0 = biasf + 288;  const float* be1 = biasf + 416;
  const float* be2 = biasf + 544;

  const f32x4 z4 = {0.f, 0.f, 0.f, 0.f};

  auto stx  = [&](int row, int col, float v) { *(short*)(x_lds + row * 136 + col * 2) = h_bits(v); };
  auto ldx4 = [&](int row, int k0) -> h16x4 { return *(const h16x4*)(x_lds + row * 136 + k0 * 2); };
  auto ldb  = [&](const short* W, int off) -> h16x4 { return *(const h16x4*)(W + off); };
  auto cvtA = [&](const u32x4& u) -> h16x4 {
    float4 v = __builtin_bit_cast(float4, u);
    h16x4 a;
    a[0] = (_Float16)v.x; a[1] = (_Float16)v.y;
    a[2] = (_Float16)v.z; a[3] = (_Float16)v.w;
    return a;
  };
  auto lo2 = [&](const u32x4& u) -> h16x4 { return __builtin_bit_cast(h16x4, (u32x2){u[0], u[1]}); };
  auto hi2 = [&](const u32x4& u) -> h16x4 { return __builtin_bit_cast(h16x4, (u32x2){u[2], u[3]}); };

  auto stageA = [&](const float* base, int rowlen, int k0, int buf) {
#pragma unroll
    for (int j = 0; j < 2; ++j) {
      int f = j * 256 + wave * 64 + lane;
      int row = f >> 3;
      int cl = (f & 7) ^ (row & 7);
      dma16(base + (size_t)(wgrow + row) * rowlen + k0 + cl * 4,
            ring + buf * 12288 + j * 4096 + wave * 1024);
    }
  };
  auto stageB = [&](const short* bsrc, int c, int buf) {
    dma16((const char*)bsrc + c * 4096 + (wave * 64 + lane) * 16,
          ring + buf * 12288 + 8192 + wave * 1024);
  };
  auto lda_ = [&](int buf, int kb2) -> u32x4 {
    return *(const u32x4*)(ring + buf * 12288 + (lrow + p) * 128 +
                           (((kb2 * 4 + q) ^ (p & 7)) * 16));
  };
  auto ldbs = [&](int buf, int kb2, int pair) -> u32x4 {
    return *(const u32x4*)(ring + buf * 12288 + 8192 + kb2 * 2048 + pair * 1024 + lane * 16);
  };

  f32x4 accX[4] = {z4, z4, z4, z4};
  {
    stageA(obs, 512, 0, 0); stageB(Bp1, 0, 0);
    for (int c = 0; c < 16; ++c) {
      asm volatile("s_waitcnt vmcnt(0)" ::: "memory");
      __builtin_amdgcn_s_barrier();
      __builtin_amdgcn_sched_barrier(0);
      if (c + 1 < 16) {
        stageA(obs, 512, (c + 1) * 32, (c + 1) & 1);
        stageB(Bp1, c + 1, (c + 1) & 1);
      }
      __builtin_amdgcn_sched_barrier(0);
      const int buf = c & 1;
#pragma unroll
      for (int kb2 = 0; kb2 < 2; ++kb2) {
        h16x4 a = cvtA(lda_(buf, kb2));
        u32x4 B0 = ldbs(buf, kb2, 0);
        u32x4 B1 = ldbs(buf, kb2, 1);
        accX[0] = MFMA16(a, lo2(B0), accX[0]);
        accX[1] = MFMA16(a, hi2(B0), accX[1]);
        accX[2] = MFMA16(a, lo2(B1), accX[2]);
        accX[3] = MFMA16(a, hi2(B1), accX[3]);
      }
    }
  }
  stageA(task, 128, 0, 0); stageB(WtP, 0, 0);
#pragma unroll
  for (int nt = 0; nt < 4; ++nt) {
    float bias = bs1[nt * 16 + p];
#pragma unroll
    for (int r = 0; r < 4; ++r)
      stx(lrow + 4 * q + r, nt * 16 + p, fmaxf(accX[nt][r] + bias, 0.f));
  }
  f32x4 accS[4] = {z4, z4, z4, z4};
#pragma unroll
  for (int kb = 0; kb < 4; ++kb) {
    h16x4 a = ldx4(lrow + p, kb * 16 + q * 4);
#pragma unroll
    for (int nt = 0; nt < 4; ++nt)
      accS[nt] = MFMA16(a, ldb(Ws2T, (nt * 16 + p) * 64 + kb * 16 + q * 4), accS[nt]);
  }
  float sf[4][4];
#pragma unroll
  for (int nt = 0; nt < 4; ++nt) {
    float bias = bs2[nt * 16 + p];
#pragma unroll
    for (int r = 0; r < 4; ++r) sf[nt][r] = fmaxf(accS[nt][r] + bias, 0.f);
  }
#pragma unroll
  for (int nt = 0; nt < 4; ++nt)
#pragma unroll
    for (int r = 0; r < 4; ++r) stx(lrow + 4 * q + r, nt * 16 + p, sf[nt][r]);
  f32x4 accT[4] = {z4, z4, z4, z4};
  {
    for (int c = 0; c < 4; ++c) {
      asm volatile("s_waitcnt vmcnt(0)" ::: "memory");
      __builtin_amdgcn_s_barrier();
      __builtin_amdgcn_sched_barrier(0);
      if (c + 1 < 4) {
        stageA(task, 128, (c + 1) * 32, (c + 1) & 1);
        stageB(WtP, c + 1, (c + 1) & 1);
      }
      __builtin_amdgcn_sched_barrier(0);
      const int buf = c & 1;
#pragma unroll
      for (int kb2 = 0; kb2 < 2; ++kb2) {
        h16x4 a = cvtA(lda_(buf, kb2));
        u32x4 B0 = ldbs(buf, kb2, 0);
        u32x4 B1 = ldbs(buf, kb2, 1);
        accT[0] = MFMA16(a, lo2(B0), accT[0]);
        accT[1] = MFMA16(a, hi2(B0), accT[1]);
        accT[2] = MFMA16(a, lo2(B1), accT[2]);
        accT[3] = MFMA16(a, hi2(B1), accT[3]);
      }
    }
  }
  float r0f[4][4];
#pragma unroll
  for (int nt = 0; nt < 4; ++nt) {
    float bias = bt[nt * 16 + p];
#pragma unroll
    for (int r = 0; r < 4; ++r)
      r0f[nt][r] = sf[nt][r] * fmaxf(accT[nt][r] + bias, 0.f);
  }
  float mfr[4][2][4];
#pragma unroll
  for (int n = 0; n < 4; ++n) {
    f32x4 acc[2] = {z4, z4};
#pragma unroll
    for (int kb = 0; kb < 4; ++kb) {
      h16x4 a = ldx4(lrow + p, kb * 16 + q * 4);
#pragma unroll
      for (int nt = 0; nt < 2; ++nt)
        acc[nt] = MFMA16(a, ldb(We0T, (n * 32 + nt * 16 + p) * 64 + kb * 16 + q * 4), acc[nt]);
    }
#pragma unroll
    for (int nt = 0; nt < 2; ++nt) {
      float bias = be0[n * 32 + nt * 16 + p];
#pragma unroll
      for (int r = 0; r < 4; ++r) mfr[n][nt][r] = fmaxf(acc[nt][r] + bias, 0.f);
    }
  }
#pragma unroll
  for (int nt = 0; nt < 4; ++nt)
#pragma unroll
    for (int r = 0; r < 4; ++r) stx(lrow + 4 * q + r, nt * 16 + p, r0f[nt][r]);
  f32x4 accA = z4;
#pragma unroll
  for (int kb = 0; kb < 4; ++kb)
    accA = MFMA16(ldx4(lrow + p, kb * 16 + q * 4), ldb(Wa0T, p * 64 + kb * 16 + q * 4), accA);
  float a0v[4];
  {
    float bias = ba0[p];
#pragma unroll
    for (int r = 0; r < 4; ++r) {
      float v = accA[r] + bias;
      float mx = fmaxf(v, __shfl_xor(v, 1));
      mx = fmaxf(mx, __shfl_xor(mx, 2));
      float e = __expf(v - mx);
      float ssum = e + __shfl_xor(e, 1);
      ssum += __shfl_xor(ssum, 2);
      a0v[r] = e / ssum;
    }
  }
#pragma unroll
  for (int r = 0; r < 4; ++r)
    *(short*)(a_lds + (lrow + 4 * q + r) * 48 + p * 2) = h_bits(a0v[r]);
  float pv[4][2][4];
#pragma unroll
  for (int i = 0; i < 4; ++i)
#pragma unroll
    for (int nt = 0; nt < 2; ++nt)
#pragma unroll
      for (int r = 0; r < 4; ++r) pv[i][nt][r] = 0.f;
  const int sbase = lane & 48;
#pragma unroll
  for (int r = 0; r < 4; ++r) {
#pragma unroll
    for (int c = 0; c < 16; ++c) {
      float av = __shfl(a0v[r], sbase | c);
      pv[c >> 2][0][r] += av * mfr[c & 3][0][r];
      pv[c >> 2][1][r] += av * mfr[c & 3][1][r];
    }
  }
  f32x4 accC[4] = {z4, z4, z4, z4};
  {
    h16x4 a = *(const h16x4*)(a_lds + (lrow + p) * 48 + q * 8);
#pragma unroll
    for (int nt = 0; nt < 4; ++nt)
      accC[nt] = MFMA16(a, ldb(Wc0T, (nt * 16 + p) * 16 + q * 4), accC[nt]);
  }
  float rf[4][4];
#pragma unroll
  for (int nt = 0; nt < 4; ++nt) {
    float bias = bc0[nt * 16 + p];
#pragma unroll
    for (int r = 0; r < 4; ++r)
      rf[nt][r] = fmaxf((accC[nt][r] + bias) * r0f[nt][r], 0.f);
  }
#pragma unroll
  for (int nt = 0; nt < 4; ++nt)
#pragma unroll
    for (int r = 0; r < 4; ++r) stx(lrow + 4 * q + r, nt * 16 + p, rf[nt][r]);
  f32x4 accA1 = z4;
#pragma unroll
  for (int kb = 0; kb < 4; ++kb)
    accA1 = MFMA16(ldx4(lrow + p, kb * 16 + q * 4), ldb(Wa1T, p * 64 + kb * 16 + q * 4), accA1);
  float a1v[4];
  {
    float bias = ba1[p];
#pragma unroll
    for (int r = 0; r < 4; ++r) {
      float v = accA1[r] + bias;
      float mx = fmaxf(v, __shfl_xor(v, 1));
      mx = fmaxf(mx, __shfl_xor(mx, 2));
      float e = __expf(v - mx);
      float ssum = e + __shfl_xor(e, 1);
      ssum += __shfl_xor(ssum, 2);
      a1v[r] = e / ssum;
    }
  }
  __syncthreads();
#pragma unroll
  for (int i = 0; i < 4; ++i)
#pragma unroll
    for (int nt = 0; nt < 2; ++nt)
#pragma unroll
      for (int r = 0; r < 4; ++r)
        *(short*)(p_lds + (i * 64 + lrow + 4 * q + r) * 80 + (nt * 16 + p) * 2) = h_bits(pv[i][nt][r]);
  float m1f[4][2][4];
#pragma unroll
  for (int n = 0; n < 4; ++n) {
    f32x4 acc[2] = {z4, z4};
#pragma unroll
    for (int kb = 0; kb < 2; ++kb) {
      h16x4 a = *(const h16x4*)(p_lds + (n * 64 + lrow + p) * 80 + kb * 32 + q * 8);
#pragma unroll
      for (int nt = 0; nt < 2; ++nt)
        acc[nt] = MFMA16(a, ldb(We1T, (n * 32 + nt * 16 + p) * 32 + kb * 16 + q * 4), acc[nt]);
    }
#pragma unroll
    for (int nt = 0; nt < 2; ++nt) {
      float bias = be1[n * 32 + nt * 16 + p];
#pragma unroll
      for (int r = 0; r < 4; ++r) m1f[n][nt][r] = fmaxf(acc[nt][r] + bias, 0.f);
    }
  }
#pragma unroll
  for (int i = 0; i < 4; ++i)
#pragma unroll
    for (int nt = 0; nt < 2; ++nt)
#pragma unroll
      for (int r = 0; r < 4; ++r) pv[i][nt][r] = 0.f;
#pragma unroll
  for (int r = 0; r < 4; ++r) {
#pragma unroll
    for (int c = 0; c < 16; ++c) {
      float av = __shfl(a1v[r], sbase | c);
      pv[c >> 2][0][r] += av * m1f[c & 3][0][r];
      pv[c >> 2][1][r] += av * m1f[c & 3][1][r];
    }
  }
#pragma unroll
  for (int i = 0; i < 4; ++i)
#pragma unroll
    for (int nt = 0; nt < 2; ++nt)
#pragma unroll
      for (int r = 0; r < 4; ++r)
        *(short*)(p_lds + (i * 64 + lrow + 4 * q + r) * 80 + (nt * 16 + p) * 2) = h_bits(pv[i][nt][r]);
  float of[2][4] = {{0.f, 0.f, 0.f, 0.f}, {0.f, 0.f, 0.f, 0.f}};
#pragma unroll
  for (int n = 0; n < 4; ++n) {
    f32x4 acc[2] = {z4, z4};
#pragma unroll
    for (int kb = 0; kb < 2; ++kb) {
      h16x4 a = *(const h16x4*)(p_lds + (n * 64 + lrow + p) * 80 + kb * 32 + q * 8);
#pragma unroll
      for (int nt = 0; nt < 2; ++nt)
        acc[nt] = MFMA16(a, ldb(We2T, (n * 32 + nt * 16 + p) * 32 + kb * 16 + q * 4), acc[nt]);
    }
#pragma unroll
    for (int nt = 0; nt < 2; ++nt) {
      float bias = be2[n * 32 + nt * 16 + p];
#pragma unroll
      for (int r = 0; r < 4; ++r) of[nt][r] += fmaxf(acc[nt][r] + bias, 0.f);
    }
  }
#pragma unroll
  for (int nt = 0; nt < 2; ++nt)
#pragma unroll
    for (int r = 0; r < 4; ++r) {
      int grow = rowblk + 4 * q + r;
      out[(size_t)grow * 32 + nt * 16 + p] = of[nt][r];
    }
}

extern "C" void kernel_launch(void* const* d_in, const int* in_sizes, int n_in,
                              void* d_out, int out_size, void* d_ws, size_t ws_size,
                              hipStream_t stream) {
  (void)in_sizes; (void)n_in; (void)out_size;
  const float* obs  = (const float*)d_in[0];
  const float* task = (const float*)d_in[1];
  const float* Ws1 = (const float*)d_in[2];  const float* bs1 = (const float*)d_in[3];
  const float* Ws2 = (const float*)d_in[4];  const float* bs2 = (const float*)d_in[5];
  const float* Wt  = (const float*)d_in[6];  const float* bt  = (const float*)d_in[7];
  const float* Wa0 = (const float*)d_in[8];  const float* ba0 = (const float*)d_in[9];
  const float* Wa1 = (const float*)d_in[10]; const float* ba1 = (const float*)d_in[11];
  const float* Wc0 = (const float*)d_in[12]; const float* bc0 = (const float*)d_in[13];
  // d_in[14]=Wc1, d_in[15]=bc1: dead code in the reference
  const float* We0 = (const float*)d_in[16]; const float* be0 = (const float*)d_in[17];
  const float* We1 = (const float*)d_in[18]; const float* be1 = (const float*)d_in[19];
  const float* We2 = (const float*)d_in[20]; const float* be2 = (const float*)d_in[21];

  short* wsh   = (short*)d_ws;
  float* biasf = (float*)((char*)d_ws + 129040);

  sm_convert_v11<<<dim3(255), dim3(256), 0, stream>>>(
      Ws1, Ws2, Wt, Wa0, Wa1, Wc0, We0, We1, We2,
      bs1, bs2, bt, ba0, ba1, bc0, be0, be1, be2,
      wsh, biasf);

  const size_t need = (size_t)(1 << 20) + (size_t)65536 * 64 * 4;  // 1MB + 16MB
  if (ws_size >= need) {
    unsigned* sr = (unsigned*)((char*)d_ws + (1 << 20));
    sm_k1_v11<<<dim3(1024), dim3(256), 0, stream>>>(obs, task, wsh, biasf, sr);
    sm_k2_v11<<<dim3(4096), dim3(64), 0, stream>>>(sr, wsh, biasf, (float*)d_out);
  } else {
    sm_fused_v11fb<<<dim3(1024), dim3(256), 0, stream>>>(
        obs, task, wsh, biasf, (float*)d_out);
  }
}